// Round 2
// baseline (1079.596 us; speedup 1.0000x reference)
//
#include <hip/hip_runtime.h>

#define B_IN   8
#define C_CH   64
#define H_IN   200
#define W_IN   320
#define H_OUT  48
#define W_OUT  320
#define N_BOX  256

// float4 with only 4-byte alignment guarantee (input window is not 16B-aligned).
typedef float float4a __attribute__((ext_vector_type(4), aligned(4)));
typedef float float4v __attribute__((ext_vector_type(4), aligned(16)));

__device__ __forceinline__ float sel4(float4a v, int off) {
    // off in [0,3]; 3 cndmask, masks are loop-invariant per lane
    float lo = (off & 1) ? v.y : v.x;
    float hi = (off & 1) ? v.w : v.z;
    return (off & 2) ? hi : lo;
}

__global__ __launch_bounds__(320) void roi_crop_kernel(
    const float* __restrict__ x,
    const int*   __restrict__ bboxes,
    const int*   __restrict__ box_img,
    float*       __restrict__ out)
{
    const int i   = blockIdx.x;    // output row 0..47
    const int box = blockIdx.y;    // box 0..255
    const int t   = threadIdx.x;   // 0..319
    const int jg  = t % 80;        // float4 group within output row
    const int cs  = t / 80;        // channel slot 0..3 (16 channels each)

    int x0 = bboxes[box * 4 + 0];
    int y0 = bboxes[box * 4 + 1];
    int x1 = bboxes[box * 4 + 2];
    int y1 = bboxes[box * 4 + 3];

    x0 = min(max(x0, 0), W_IN - 1);
    y0 = min(max(y0, 0), H_IN - 1);
    x1 = min(max(x1, 0), W_IN - 1);
    y1 = min(max(y1, 0), H_IN - 1);
    x1 = max(x1, x0);
    y1 = max(y1, y0);

    const int h = y1 - y0 + 1;
    const int w = x1 - x0 + 1;

    const int r   = y0 + (i * h) / H_OUT;
    const int img = box_img[box];

    const int j0 = jg * 4;
    const int c0 = x0 + ((j0 + 0) * w) / W_OUT;
    const int c1 = x0 + ((j0 + 1) * w) / W_OUT;
    const int c2 = x0 + ((j0 + 2) * w) / W_OUT;
    const int c3 = x0 + ((j0 + 3) * w) / W_OUT;

    // All four cols fit in [base, base+3]: col(j0+3)-col(j0) <= ceil(3w/320) <= 3.
    const int base = min(c0, W_IN - 4);
    const int o0 = c0 - base, o1 = c1 - base, o2 = c2 - base, o3 = c3 - base;

    const int cbase = cs * 16;  // this thread's first channel
    const float* __restrict__ src =
        x + (size_t)img * (C_CH * H_IN * W_IN)
          + (size_t)cbase * (H_IN * W_IN)
          + (size_t)r * W_IN + base;
    float* __restrict__ dst =
        out + (size_t)box * (C_CH * H_OUT * W_OUT)
            + (size_t)cbase * (H_OUT * W_OUT)
            + (size_t)i * W_OUT + j0;

    #pragma unroll 4
    for (int k = 0; k < 16; ++k) {
        float4a v = *(const float4a*)(src + (size_t)k * (H_IN * W_IN));
        float4v o;
        o.x = sel4(v, o0);
        o.y = sel4(v, o1);
        o.z = sel4(v, o2);
        o.w = sel4(v, o3);
        *(float4v*)(dst + (size_t)k * (H_OUT * W_OUT)) = o;
    }
}

extern "C" void kernel_launch(void* const* d_in, const int* in_sizes, int n_in,
                              void* d_out, int out_size, void* d_ws, size_t ws_size,
                              hipStream_t stream) {
    const float* x       = (const float*)d_in[0];
    const int*   bboxes  = (const int*)d_in[1];
    const int*   box_img = (const int*)d_in[2];
    float*       out     = (float*)d_out;

    dim3 grid(H_OUT, N_BOX);   // (48, 256)
    dim3 block(320);
    roi_crop_kernel<<<grid, block, 0, stream>>>(x, bboxes, box_img, out);
}

// Round 3
// 1065.528 us; speedup vs baseline: 1.0132x; 1.0132x over previous
//
#include <hip/hip_runtime.h>

#define B_IN   8
#define C_CH   64
#define H_IN   200
#define W_IN   320
#define H_OUT  48
#define W_OUT  320
#define N_BOX  256

// float4 with only 4-byte alignment guarantee (input window is not 16B-aligned).
typedef float float4a __attribute__((ext_vector_type(4), aligned(4)));
typedef float float4v __attribute__((ext_vector_type(4), aligned(16)));

__device__ __forceinline__ float sel4(float4a v, int off) {
    float lo = (off & 1) ? v.y : v.x;
    float hi = (off & 1) ? v.w : v.z;
    return (off & 2) ? hi : lo;
}

__global__ __launch_bounds__(320) void roi_crop_kernel(
    const float* __restrict__ x,
    const int*   __restrict__ bboxes,
    const int*   __restrict__ box_img,
    float*       __restrict__ out)
{
    const int i   = blockIdx.x;    // output row 0..47
    const int box = blockIdx.y;    // box 0..255
    const int t   = threadIdx.x;   // 0..319
    const int jg  = t % 80;        // float4 group within output row
    const int cs  = t / 80;        // channel slot 0..3 (16 channels each)

    int x0 = bboxes[box * 4 + 0];
    int y0 = bboxes[box * 4 + 1];
    int x1 = bboxes[box * 4 + 2];
    int y1 = bboxes[box * 4 + 3];

    x0 = min(max(x0, 0), W_IN - 1);
    y0 = min(max(y0, 0), H_IN - 1);
    x1 = min(max(x1, 0), W_IN - 1);
    y1 = min(max(y1, 0), H_IN - 1);
    x1 = max(x1, x0);
    y1 = max(y1, y0);

    const int h = y1 - y0 + 1;
    const int w = x1 - x0 + 1;

    const int r   = y0 + (i * h) / H_OUT;
    const int img = box_img[box];

    const int j0 = jg * 4;
    const int c0 = x0 + ((j0 + 0) * w) / W_OUT;
    const int c1 = x0 + ((j0 + 1) * w) / W_OUT;
    const int c2 = x0 + ((j0 + 2) * w) / W_OUT;
    const int c3 = x0 + ((j0 + 3) * w) / W_OUT;

    // All four cols fit in [base, base+3]: col(j0+3)-col(j0) <= ceil(3w/320) <= 3.
    const int base = min(c0, W_IN - 4);
    const int o0 = c0 - base, o1 = c1 - base, o2 = c2 - base, o3 = c3 - base;

    const int cbase = cs * 16;
    const float* __restrict__ src =
        x + (size_t)img * (C_CH * H_IN * W_IN)
          + (size_t)cbase * (H_IN * W_IN)
          + (size_t)r * W_IN + base;
    float* __restrict__ dst =
        out + (size_t)box * (C_CH * H_OUT * W_OUT)
            + (size_t)cbase * (H_OUT * W_OUT)
            + (size_t)i * W_OUT + j0;

    // Phase A: issue ALL 16 loads (16 outstanding vmem ops per wave -> covers
    // ~900-cycle cold-miss latency with ~30 waves/CU).
    float4a v[16];
    #pragma unroll
    for (int k = 0; k < 16; ++k) {
        v[k] = *(const float4a*)(src + (size_t)k * (H_IN * W_IN));
    }

    // Phase B: select + nontemporal store (keep output out of L2/L3 so the
    // 131 MB input stays cache-resident).
    #pragma unroll
    for (int k = 0; k < 16; ++k) {
        float4v o;
        o.x = sel4(v[k], o0);
        o.y = sel4(v[k], o1);
        o.z = sel4(v[k], o2);
        o.w = sel4(v[k], o3);
        __builtin_nontemporal_store(o, (float4v*)(dst + (size_t)k * (H_OUT * W_OUT)));
    }
}

extern "C" void kernel_launch(void* const* d_in, const int* in_sizes, int n_in,
                              void* d_out, int out_size, void* d_ws, size_t ws_size,
                              hipStream_t stream) {
    const float* x       = (const float*)d_in[0];
    const int*   bboxes  = (const int*)d_in[1];
    const int*   box_img = (const int*)d_in[2];
    float*       out     = (float*)d_out;

    dim3 grid(H_OUT, N_BOX);   // (48, 256)
    dim3 block(320);
    roi_crop_kernel<<<grid, block, 0, stream>>>(x, bboxes, box_img, out);
}

// Round 4
// 1052.617 us; speedup vs baseline: 1.0256x; 1.0123x over previous
//
#include <hip/hip_runtime.h>

#define C_CH   64
#define H_IN   200
#define W_IN   320
#define H_OUT  48
#define W_OUT  320
#define N_BOX  256

typedef float float4v __attribute__((ext_vector_type(4), aligned(16)));

// One block per (channel, box). 320 threads.
// Phase 1: stage the 48 needed input rows (full width) into LDS — coalesced.
// Phase 2: thread t = output column j; 48 stride-<=1 LDS reads + one fully
//          contiguous 61440B nontemporal store stream per block.
__global__ __launch_bounds__(320, 2) void roi_crop_kernel(
    const float* __restrict__ x,
    const int*   __restrict__ bboxes,
    const int*   __restrict__ box_img,
    float*       __restrict__ out)
{
    __shared__ float tile[H_OUT * W_OUT];   // 48*320*4 = 61440 B

    const int c   = blockIdx.x;   // channel 0..63
    const int box = blockIdx.y;   // box     0..255
    const int t   = threadIdx.x;  // 0..319

    int x0 = bboxes[box * 4 + 0];
    int y0 = bboxes[box * 4 + 1];
    int x1 = bboxes[box * 4 + 2];
    int y1 = bboxes[box * 4 + 3];

    x0 = min(max(x0, 0), W_IN - 1);
    y0 = min(max(y0, 0), H_IN - 1);
    x1 = min(max(x1, 0), W_IN - 1);
    y1 = min(max(y1, 0), H_IN - 1);
    x1 = max(x1, x0);
    y1 = max(y1, y0);

    const int h = y1 - y0 + 1;
    const int w = x1 - x0 + 1;
    const int img = box_img[box];

    const float* __restrict__ plane_in =
        x + ((size_t)img * C_CH + c) * (H_IN * W_IN);
    float* __restrict__ plane_out =
        out + ((size_t)box * C_CH + c) * (H_OUT * W_OUT);

    // ---- Phase 1: stage 48 rows x 320 cols. 3840 float4s / 320 threads = 12 each.
    float4v v[12];
    #pragma unroll
    for (int k = 0; k < 12; ++k) {
        const int p   = t + k * 320;      // float4 index 0..3839
        const int i   = p / 80;           // output row (80 float4 per row)
        const int wrd = p % 80;           // float4 within row
        const int r   = y0 + (i * h) / H_OUT;
        v[k] = *(const float4v*)(plane_in + (size_t)r * W_IN + wrd * 4);
    }
    #pragma unroll
    for (int k = 0; k < 12; ++k) {
        const int p = t + k * 320;
        *(float4v*)&tile[p * 4] = v[k];
    }
    __syncthreads();

    // ---- Phase 2: gather + contiguous store. j = t.
    const int col = x0 + (t * w) / W_OUT;  // adjacent lanes: col step <= 1 → conflict-free
    #pragma unroll 8
    for (int i = 0; i < H_OUT; ++i) {
        const float val = tile[i * W_OUT + col];
        __builtin_nontemporal_store(val, plane_out + i * W_OUT + t);
    }
}

extern "C" void kernel_launch(void* const* d_in, const int* in_sizes, int n_in,
                              void* d_out, int out_size, void* d_ws, size_t ws_size,
                              hipStream_t stream) {
    const float* x       = (const float*)d_in[0];
    const int*   bboxes  = (const int*)d_in[1];
    const int*   box_img = (const int*)d_in[2];
    float*       out     = (float*)d_out;

    dim3 grid(C_CH, N_BOX);   // (64, 256) = 16384 blocks
    dim3 block(320);
    roi_crop_kernel<<<grid, block, 0, stream>>>(x, bboxes, box_img, out);
}